// Round 8
// baseline (1401.058 us; speedup 1.0000x reference)
//
#include <hip/hip_runtime.h>

// Problem constants: N=Na=10000, d_in=256, d_out=64, n_rel=3
#define NN    10000
#define NA    10000
#define DIN   256
#define DOUT  64
#define INV_T (1.0f / 0.07f)
#define CAP   1024   // max adjacency-true entries per row; Binomial(10000,0.01) max ~150

typedef unsigned int uv4 __attribute__((ext_vector_type(4)));  // nt-loadable uint4

// adjs layout: int32-per-bool (A/B-verified: R1 byte-layout failed with
// wrong-column signature, R2 runtime-detect passed).

// ---- Fused kernel: proj + sparse masked-softmax attention. One block/row. ----
// R7 scan/proj structure + single-pass online-softmax epilogue.
__global__ __launch_bounds__(256) void attn_kernel(
    const float* __restrict__ x,        // [NN, DOUT]
    const float* __restrict__ weight,   // [n_rel]
    const unsigned int* __restrict__ adjs, // [n_rel, NA, NN] int32 bools
    const int*   __restrict__ idxp,     // [1]
    const float* __restrict__ anchor,   // [NA, DIN]
    const float* __restrict__ wt,       // [DIN, DOUT]
    float* __restrict__ out)            // [NA, DOUT]
{
    __shared__ float arow[DIN];   // anchor row
    __shared__ float pr[DOUT];    // projected row
    __shared__ int   jl[CAP];     // compacted hit list
    __shared__ float red[256];
    __shared__ float wred[8];     // per-wave online-softmax partials
    __shared__ int   cnt;

    const int t    = threadIdx.x;
    const int row  = blockIdx.x;
    const int w    = t >> 6;      // wave id 0..3
    const int lane = t & 63;      // lane == output column c in the fused pass

    // stage anchor row (256 floats = 64 float4) + zero the compaction counter
    if (t < 64) ((float4*)arow)[t] =
        ((const float4*)(anchor + (size_t)row * DIN))[t];
    if (t == 0) cnt = 0;
    __syncthreads();

    const int idx = idxp[0];

    // ---- Phase A: NT scan of adj row (2500 uint4 = 10000 int32), compact ----
    {
        const uv4* ar = (const uv4*)(adjs + ((size_t)idx * NA + row) * NN);
#pragma unroll
        for (int it = 0; it < 10; ++it) {
            const int cch = t + 256 * it;
            if (cch < NN / 4) {
                uv4 v = __builtin_nontemporal_load(ar + cch);
                if (v.x | v.y | v.z | v.w) {
                    unsigned int ws4[4] = {v.x, v.y, v.z, v.w};
#pragma unroll
                    for (int ww = 0; ww < 4; ++ww) {
                        if (ws4[ww]) {
                            int pos = atomicAdd(&cnt, 1);
                            if (pos < CAP) jl[pos] = cch * 4 + ww;
                        }
                    }
                }
            }
        }
    }

    // ---- Phase P (same barrier interval): proj[row] = anchor[row] @ wt ----
    {
        const int seg = t >> 6, c = t & 63;
        float acc = 0.f;
        const int k0 = seg * 64;
#pragma unroll 8
        for (int k = k0; k < k0 + 64; ++k)
            acc = fmaf(arow[k], wt[k * DOUT + c], acc);  // wt coalesced across c
        red[t] = acc;
    }
    __syncthreads();   // finalizes cnt, jl, and proj partials

    if (t < DOUT) pr[t] = red[t] + red[64 + t] + red[128 + t] + red[192 + t];
    int nc = cnt; if (nc > CAP) nc = CAP;
    __syncthreads();

    if (nc == 0) {  // cannot occur at 1% density with this seed; stay defined
        if (t < DOUT) out[(size_t)row * DOUT + t] = 0.f;
        return;
    }

    // ---- Fused online-softmax pass: one x-row load serves score AND PV ----
    // Wave w owns s = w, w+4, w+8, ...  All per-wave state is lane-uniform
    // except acc (acc[lane] accumulates column c = lane).
    const float prc = pr[lane];
    float m_w = -3.4e38f, l_w = 0.f, acc = 0.f;
    int s = w;
    // 2x manual unroll: interleave two independent 64-lane butterfly reduces
    for (; s + 4 < nc; s += 8) {
        const int j0 = jl[s], j1 = jl[s + 4];          // wave-uniform broadcasts
        const float xv0 = x[(size_t)j0 * DOUT + lane]; // coalesced 256B each
        const float xv1 = x[(size_t)j1 * DOUT + lane];
        float d0 = prc * xv0, d1 = prc * xv1;
#pragma unroll
        for (int o = 32; o > 0; o >>= 1) {
            d0 += __shfl_xor(d0, o);
            d1 += __shfl_xor(d1, o);
        }
        d0 *= INV_T; d1 *= INV_T;
        const float mnew  = fmaxf(m_w, fmaxf(d0, d1));
        const float alpha = __expf(m_w - mnew);        // 0 on first trip
        const float p0    = __expf(d0 - mnew);
        const float p1    = __expf(d1 - mnew);
        acc = acc * alpha + p0 * xv0 + p1 * xv1;
        l_w = l_w * alpha + p0 + p1;
        m_w = mnew;
    }
    if (s < nc) {                                      // tail element
        const int j = jl[s];
        const float xv = x[(size_t)j * DOUT + lane];
        float d = prc * xv;
#pragma unroll
        for (int o = 32; o > 0; o >>= 1) d += __shfl_xor(d, o);
        d *= INV_T;
        const float mnew  = fmaxf(m_w, d);
        const float alpha = __expf(m_w - mnew);
        const float p     = __expf(d - mnew);
        acc = acc * alpha + p * xv;
        l_w = l_w * alpha + p;
        m_w = mnew;
    }

    // ---- Merge the 4 per-wave online states ----
    if (lane == 0) wred[w] = m_w;
    __syncthreads();
    const float m = fmaxf(fmaxf(wred[0], wred[1]), fmaxf(wred[2], wred[3]));
    const float f = __expf(m_w - m);   // wave with no elements: exp(-3.4e38-m)=0
    if (lane == 0) wred[4 + w] = l_w * f;
    red[t] = acc * f;
    __syncthreads();
    const float scale = weight[idx] / (wred[4] + wred[5] + wred[6] + wred[7]);
    if (t < DOUT) {
        float o = (red[t] + red[64 + t] + red[128 + t] + red[192 + t]) * scale;
        __builtin_nontemporal_store(o, out + (size_t)row * DOUT + t);
    }
}

extern "C" void kernel_launch(void* const* d_in, const int* in_sizes, int n_in,
                              void* d_out, int out_size, void* d_ws, size_t ws_size,
                              hipStream_t stream) {
    const float*        x      = (const float*)d_in[0];
    const float*        weight = (const float*)d_in[1];
    const unsigned int* adjs   = (const unsigned int*)d_in[2];
    const int*          idxp   = (const int*)d_in[3];
    const float*        anchor = (const float*)d_in[4];
    const float*        wt     = (const float*)d_in[5];
    float*              out    = (float*)d_out;

    attn_kernel<<<NA, 256, 0, stream>>>(x, weight, adjs, idxp, anchor, wt, out);
}